// Round 9
// baseline (245.447 us; speedup 1.0000x reference)
//
#include <hip/hip_runtime.h>

// LIF constants (match reference); K = exp(-1/20)
#define KOEFF 0.951229424500714f
#define KP2   0.904837418035960f   // K^2
#define KP4   0.818730753077982f   // K^4
#define KP8   0.670320046035639f   // K^8
#define KP16  0.449328964117222f   // K^16
#define K64   0.040762203978366f   // K^64
#define LOG2K (-0.07213475204444817f) // log2(K)

typedef unsigned short u16;
typedef __attribute__((ext_vector_type(8))) short short8;   // 8 bf16 (MFMA A/B frag)
typedef __attribute__((ext_vector_type(4))) float f32x4;    // MFMA C/D frag

__device__ __forceinline__ u16 f2bf(float f) {
  unsigned int v = __float_as_uint(f);
  unsigned int r = (v + 0x7FFFu + ((v >> 16) & 1u)) >> 16;
  return (u16)r;
}

// ---------------------------------------------------------------------------
// Kernel 1 (merged prep): blockIdx.x partitions two independent jobs:
//   [0,4096)    : X [64][512 j][512 t] fp32 -> XT16 [64][512 t][512 j] bf16
//   [4096,7168) : W rows 512..2047 cols 0..511 -> bf16 Whi[1536][512]; zero flags
// ---------------------------------------------------------------------------
__global__ __launch_bounds__(256) void k_prep(const float* __restrict__ X, const float* __restrict__ W,
                                              u16* __restrict__ XT, u16* __restrict__ Whi,
                                              int* __restrict__ flags) {
  __shared__ float tile[64][65];
  const int blk = blockIdx.x;
  if (blk < 4096) {
    const int b  = blk >> 6;
    const int r2 = blk & 63;
    const int j0 = (r2 & 7) * 64;
    const int t0 = (r2 >> 3) * 64;
    const float* src = X + ((size_t)b * 512 + j0) * 512 + t0;
    for (int e = threadIdx.x; e < 64 * 16; e += 256) {
      int r = e >> 4, c = e & 15;
      float4 v = *(const float4*)(src + (size_t)r * 512 + c * 4);
      tile[r][c * 4 + 0] = v.x; tile[r][c * 4 + 1] = v.y;
      tile[r][c * 4 + 2] = v.z; tile[r][c * 4 + 3] = v.w;
    }
    __syncthreads();
    u16* dst = XT + ((size_t)b * 512 + t0) * 512 + j0;
    for (int e = threadIdx.x; e < 64 * 16; e += 256) {
      int tr = e >> 4, c = e & 15;
      ushort4 o;
      o.x = f2bf(tile[c * 4 + 0][tr]); o.y = f2bf(tile[c * 4 + 1][tr]);
      o.z = f2bf(tile[c * 4 + 2][tr]); o.w = f2bf(tile[c * 4 + 3][tr]);
      *(ushort4*)(dst + (size_t)tr * 512 + c * 4) = o;
    }
  } else {
    if (blk == 4096 && threadIdx.x < 64) flags[threadIdx.x] = 0;
    int p = (blk - 4096) * 256 + threadIdx.x;   // exactly covers 1536*512
    int i = p >> 9, j = p & 511;
    Whi[p] = f2bf(W[(size_t)(512 + i) * 2048 + j]);
  }
}

// ---------------------------------------------------------------------------
// Kernel 2: GEMM + analytic chunk summary (NO U tensor).
// 128x128 tile, BK=64, 4 waves each 64x64 (R6 proven structure), T2 swizzle
// via pre-swizzled global source (rule #21). Each wave's 64-t span is one
// chunk c = nt*2+wc. Epilogue: in-register weighted Kogge-Stone scan over t,
// then per (neuron, chunk) emit:
//   P     = chunk total  sum_{tau} K^{63-tau} u_tau        (carry chain)
//   IVmin = min_tau (1 - s_local(tau)) * K^{-(tau+1)}      (spike boundary)
//   IVmax = max_tau (-1 - s_local(tau)) * K^{-(tau+1)}     (clamp boundary)
// Chunk violates iff carry >= IVmin or carry <= IVmax (S is affine monotone
// in the carry). 9.4 MB of summaries replace 100 MB of U.
// ---------------------------------------------------------------------------
__global__ __launch_bounds__(256) void k_gemm(const u16* __restrict__ A, const u16* __restrict__ Bx,
                                              float* __restrict__ P, float* __restrict__ IVmin,
                                              float* __restrict__ IVmax) {
  __shared__ u16 lA[128 * 64];
  __shared__ u16 lB[128 * 64];
  const int b    = blockIdx.y;
  const int mt   = blockIdx.x >> 2;
  const int nt   = blockIdx.x & 3;
  const int tid  = threadIdx.x;
  const int wv   = tid >> 6;
  const int lane = tid & 63;
  const int tl   = lane & 15;      // t within 16
  const int qg   = lane >> 4;      // 0..3
  const int l7   = lane & 7;
  const int wr   = wv >> 1, wc = wv & 1;

  f32x4 acc[4][4];
#pragma unroll
  for (int mi = 0; mi < 4; ++mi)
#pragma unroll
    for (int ni = 0; ni < 4; ++ni) acc[mi][ni] = (f32x4)0.0f;

  const u16* gA = A + (size_t)mt * 128 * 512;
  const u16* gB = Bx + ((size_t)b * 512 + nt * 128) * 512;

  for (int k0 = 0; k0 < 512; k0 += 64) {
#pragma unroll
    for (int it = 0; it < 4; ++it) {
      int byteoff = wv * 4096 + it * 1024 + lane * 16;
      int row   = byteoff >> 7;          // 128B per LDS row (64 bf16 of k)
      int chunk = (byteoff >> 4) & 7;    // 16B chunk within row
      int ksub  = (chunk ^ (row & 7)) * 8;   // pre-swizzled global source
      int ldsoff = wv * 2048 + it * 512;     // linear LDS dest (wave-uniform)
      __builtin_amdgcn_global_load_lds(
          (const __attribute__((address_space(1))) void*)(gA + (size_t)row * 512 + k0 + ksub),
          (__attribute__((address_space(3))) void*)(lA + ldsoff), 16, 0, 0);
      __builtin_amdgcn_global_load_lds(
          (const __attribute__((address_space(1))) void*)(gB + (size_t)row * 512 + k0 + ksub),
          (__attribute__((address_space(3))) void*)(lB + ldsoff), 16, 0, 0);
    }
    __syncthreads();
#pragma unroll
    for (int kk = 0; kk < 2; ++kk) {
      short8 ah[4], bb[4];
      const int kc = kk * 4 + qg;            // chunk index 0..7
#pragma unroll
      for (int mi = 0; mi < 4; ++mi) {
        int m = wr * 64 + mi * 16 + tl;
        ah[mi] = *(const short8*)&lA[m * 64 + (((kc ^ l7) & 7) << 3)];
      }
#pragma unroll
      for (int ni = 0; ni < 4; ++ni) {
        int n = wc * 64 + ni * 16 + tl;
        bb[ni] = *(const short8*)&lB[n * 64 + (((kc ^ l7) & 7) << 3)];
      }
#pragma unroll
      for (int mi = 0; mi < 4; ++mi)
#pragma unroll
        for (int ni = 0; ni < 4; ++ni)
          acc[mi][ni] = __builtin_amdgcn_mfma_f32_16x16x32_bf16(ah[mi], bb[ni], acc[mi][ni], 0, 0, 0);
    }
    __syncthreads();
  }

  // ---- epilogue: in-register scan + chunk summaries (no U store)
  {
    const int c = nt * 2 + wc;       // this wave's time chunk (64 t)
    // S1: weighted Kogge-Stone inclusive scan within each 16-lane t-group
    const float kd[4] = {KOEFF, KP2, KP4, KP8};
    const int   dd[4] = {1, 2, 4, 8};
#pragma unroll
    for (int rd = 0; rd < 4; ++rd) {
      const float kw = kd[rd];
      const int dl = dd[rd];
#pragma unroll
      for (int mi = 0; mi < 4; ++mi)
#pragma unroll
        for (int ni = 0; ni < 4; ++ni)
#pragma unroll
          for (int q = 0; q < 4; ++q) {
            float g = __shfl_up(acc[mi][ni][q], dl, 16);
            if (tl < dl) g = 0.f;
            acc[mi][ni][q] = fmaf(kw, g, acc[mi][ni][q]);
          }
    }
    const float kp  = exp2f(LOG2K * (float)(tl + 1));    // K^{tl+1}
    const float krt = exp2f(-LOG2K * (float)(tl + 1));   // K^{-(tl+1)}
    const float K16R[4] = {1.f, 2.225540928f, 4.953032424f, 11.02317638f};  // K^{-16 ni}
    float cmn[4][4], cmx[4][4], Pv[4][4];
#pragma unroll
    for (int mi = 0; mi < 4; ++mi)
#pragma unroll
      for (int q = 0; q < 4; ++q) {
        float pc = 0.f;                       // in-chunk prefix carry (block scan)
        float cmin_v = 3.4e38f, cmax_v = -3.4e38f;
#pragma unroll
        for (int ni = 0; ni < 4; ++ni) {
          float sl = fmaf(kp, pc, acc[mi][ni][q]);   // s_local at tau = ni*16+tl
          float kr = krt * K16R[ni];                 // K^{-(tau+1)}
          cmin_v = fminf(cmin_v, (1.0f - sl) * kr);
          cmax_v = fmaxf(cmax_v, (-1.0f - sl) * kr);
          pc = fmaf(pc, KP16, __shfl(acc[mi][ni][q], 15, 16));  // += block total
        }
        Pv[mi][q] = pc;                        // chunk total (= s_local(63))
        cmn[mi][q] = cmin_v;
        cmx[mi][q] = cmax_v;
      }
    // reduce boundaries over the 16 t-lanes
#pragma unroll
    for (int off = 1; off < 16; off <<= 1)
#pragma unroll
      for (int mi = 0; mi < 4; ++mi)
#pragma unroll
        for (int q = 0; q < 4; ++q) {
          cmn[mi][q] = fminf(cmn[mi][q], __shfl_xor(cmn[mi][q], off, 16));
          cmx[mi][q] = fmaxf(cmx[mi][q], __shfl_xor(cmx[mi][q], off, 16));
        }
    if (tl == 0) {
      const size_t base = ((size_t)b * 8 + c) * 1536 + mt * 128 + wr * 64 + (qg << 2);
#pragma unroll
      for (int mi = 0; mi < 4; ++mi)
#pragma unroll
        for (int q = 0; q < 4; ++q) {
          P[base + mi * 16 + q]     = Pv[mi][q];
          IVmin[base + mi * 16 + q] = cmn[mi][q];
          IVmax[base + mi * 16 + q] = cmx[mi][q];
        }
    }
  }
}

// ---------------------------------------------------------------------------
// Kernel 3: zero the output + run the carry chain against the chunk intervals.
// blk < 384: grid-stride float4 zero of out (flagged batches are overwritten
// by k_fix afterwards). blk >= 384: thread (b,i) chains the 8 chunk carries
// and flags the batch if any chunk's carry crosses its spike/clamp boundary
// (conservative 1e-3 slack; false-positive -> exact recompute, still correct).
// ---------------------------------------------------------------------------
__global__ __launch_bounds__(256) void k_check(const float* __restrict__ P, const float* __restrict__ IVmin,
                                               const float* __restrict__ IVmax, float* __restrict__ out,
                                               int* __restrict__ flags) {
  const int blk = blockIdx.x;
  if (blk < 384) {
    float4 z = make_float4(0.f, 0.f, 0.f, 0.f);
    float4* o = (float4*)out;
    for (int idx = blk * 256 + threadIdx.x; idx < 64 * 256 * 512 / 4; idx += 384 * 256)
      o[idx] = z;
  } else {
    const int g = (blk - 384) * 256 + threadIdx.x;   // 0..98303
    const int b = g / 1536;
    const int i = g - b * 1536;
    const size_t base = (size_t)b * 8 * 1536 + i;
    float c = 0.f;          // state entering chunk d
    bool viol = false;
#pragma unroll
    for (int d = 0; d < 8; ++d) {
      float hi = IVmin[base + (size_t)d * 1536];
      float lo = IVmax[base + (size_t)d * 1536];
      viol = viol || (c >= hi - 1e-3f) || (c <= lo + 1e-3f);
      c = fmaf(c, K64, P[base + (size_t)d * 1536]);
    }
    if (viol) atomicOr(&flags[b], 1);
  }
}

// ---------------------------------------------------------------------------
// Kernel 4: exact backstop, gated per batch. Full LIF dynamics (recurrence,
// refractory, clamp) from X and W directly. Expected: immediate exit.
// ---------------------------------------------------------------------------
__global__ __launch_bounds__(256) void k_fix(const float* __restrict__ X, const float* __restrict__ W,
                                             const int* __restrict__ flags, float* __restrict__ out) {
  const int b = blockIdx.x;
  if (flags[b] == 0) return;   // uniform per block
  const int tid = threadIdx.x;
  const int wv = tid >> 6, lane = tid & 63;
  float st[6], rf[6];
#pragma unroll
  for (int r = 0; r < 6; ++r) { st[r] = 0.f; rf[r] = 0.f; }
  __shared__ unsigned int mask[64];
  for (int w = tid; w < 64; w += 256) mask[w] = 0u;
  __syncthreads();
  for (int t = 0; t < 512; ++t) {
    {
      float x = X[((size_t)b * 512 + tid) * 512 + t];
      unsigned long long bl = __ballot(x > 0.5f);
      if (lane == 0) { mask[2 * wv] = (unsigned int)bl; mask[2 * wv + 1] = (unsigned int)(bl >> 32); }
      x = X[((size_t)b * 512 + 256 + tid) * 512 + t];
      bl = __ballot(x > 0.5f);
      if (lane == 0) { mask[8 + 2 * wv] = (unsigned int)bl; mask[9 + 2 * wv] = (unsigned int)(bl >> 32); }
    }
    __syncthreads();
    float add[6] = {0.f, 0.f, 0.f, 0.f, 0.f, 0.f};
    for (int wd = 0; wd < 64; ++wd) {
      unsigned int m = mask[wd];
      while (m) {
        int bitp = __ffs(m) - 1;
        m &= m - 1;
        int j = wd * 32 + bitp;
#pragma unroll
        for (int r = 0; r < 6; ++r) add[r] += W[(size_t)(512 + tid + 256 * r) * 2048 + j];
      }
    }
    bool sp[6];
#pragma unroll
    for (int r = 0; r < 6; ++r) {
      float a = fmaf(st[r], KOEFF, add[r]);
      if (rf[r] > 0.f) a = 0.f;
      sp[r] = a >= 1.0f;
      rf[r] -= 1.f;
      if (sp[r]) rf[r] = 2.f;
      if (a < -1.f) a = -1.f;
      st[r] = a;
      int gi = 512 + tid + 256 * r;
      if (gi >= 1792) out[((size_t)b * 256 + (gi - 1792)) * 512 + t] = sp[r] ? 1.f : 0.f;
    }
    __syncthreads();
#pragma unroll
    for (int r = 0; r < 6; ++r) {
      unsigned long long bl = __ballot(sp[r]);
      if (lane == 0) {
        mask[16 + 8 * r + 2 * wv] = (unsigned int)bl;
        mask[17 + 8 * r + 2 * wv] = (unsigned int)(bl >> 32);
      }
    }
    __syncthreads();
  }
}

// ---------------------------------------------------------------------------
// Fallback exact simulator (ungated; used when ws too small for fast path)
// ---------------------------------------------------------------------------
__global__ __launch_bounds__(256) void k_exact(const float* __restrict__ X, const float* __restrict__ W,
                                               float* __restrict__ out) {
  const int b = blockIdx.x, tid = threadIdx.x;
  const int wv = tid >> 6, lane = tid & 63;
  float st[6], rf[6];
#pragma unroll
  for (int r = 0; r < 6; ++r) { st[r] = 0.f; rf[r] = 0.f; }
  __shared__ unsigned int mask[64];
  for (int w = tid; w < 64; w += 256) mask[w] = 0u;
  __syncthreads();
  for (int t = 0; t < 512; ++t) {
    {
      float x = X[((size_t)b * 512 + tid) * 512 + t];
      unsigned long long bl = __ballot(x > 0.5f);
      if (lane == 0) { mask[2 * wv] = (unsigned int)bl; mask[2 * wv + 1] = (unsigned int)(bl >> 32); }
      x = X[((size_t)b * 512 + 256 + tid) * 512 + t];
      bl = __ballot(x > 0.5f);
      if (lane == 0) { mask[8 + 2 * wv] = (unsigned int)bl; mask[9 + 2 * wv] = (unsigned int)(bl >> 32); }
    }
    __syncthreads();
    float add[6] = {0.f, 0.f, 0.f, 0.f, 0.f, 0.f};
    for (int wd = 0; wd < 64; ++wd) {
      unsigned int m = mask[wd];
      while (m) {
        int bitp = __ffs(m) - 1;
        m &= m - 1;
        int j = wd * 32 + bitp;
#pragma unroll
        for (int r = 0; r < 6; ++r) add[r] += W[(size_t)(512 + tid + 256 * r) * 2048 + j];
      }
    }
    bool sp[6];
#pragma unroll
    for (int r = 0; r < 6; ++r) {
      float a = fmaf(st[r], KOEFF, add[r]);
      if (rf[r] > 0.f) a = 0.f;
      sp[r] = a >= 1.0f;
      rf[r] -= 1.f;
      if (sp[r]) rf[r] = 2.f;
      if (a < -1.f) a = -1.f;
      st[r] = a;
      int gi = 512 + tid + 256 * r;
      if (gi >= 1792) out[((size_t)b * 256 + (gi - 1792)) * 512 + t] = sp[r] ? 1.f : 0.f;
    }
    __syncthreads();
#pragma unroll
    for (int r = 0; r < 6; ++r) {
      unsigned long long bl = __ballot(sp[r]);
      if (lane == 0) {
        mask[16 + 8 * r + 2 * wv] = (unsigned int)bl;
        mask[17 + 8 * r + 2 * wv] = (unsigned int)(bl >> 32);
      }
    }
    __syncthreads();
  }
}

// ---------------------------------------------------------------------------
extern "C" void kernel_launch(void* const* d_in, const int* in_sizes, int n_in,
                              void* d_out, int out_size, void* d_ws, size_t ws_size,
                              hipStream_t stream) {
  const float* X = (const float*)d_in[0];   // [64][512][512]
  const float* W = (const float*)d_in[1];   // [2048][2048]
  float* out = (float*)d_out;               // [64][256][512]
  char* ws = (char*)d_ws;

  const size_t SZ_XT = 64ull * 512 * 512 * 2;    // 33,554,432
  const size_t SZ_WH = 1536ull * 512 * 2;        //  1,572,864
  const size_t SZ_P  = 64ull * 8 * 1536 * 4;     //  3,145,728 (x3: P, IVmin, IVmax)
  const size_t SZ_FL = 256;
  const size_t NEED_FULL = SZ_XT + SZ_WH + 3 * SZ_P + SZ_FL;   // ~44.6 MB

  if (ws_size >= NEED_FULL) {
    u16*   XT   = (u16*)ws;
    u16*   Whi  = (u16*)(ws + SZ_XT);
    float* P    = (float*)(ws + SZ_XT + SZ_WH);
    float* IVmn = (float*)(ws + SZ_XT + SZ_WH + SZ_P);
    float* IVmx = (float*)(ws + SZ_XT + SZ_WH + 2 * SZ_P);
    int*   FL   = (int*)(ws + SZ_XT + SZ_WH + 3 * SZ_P);
    k_prep<<<7168, 256, 0, stream>>>(X, W, XT, Whi, FL);
    k_gemm<<<dim3(48, 64), 256, 0, stream>>>(Whi, XT, P, IVmn, IVmx);
    k_check<<<768, 256, 0, stream>>>(P, IVmn, IVmx, out, FL);
    k_fix<<<64, 256, 0, stream>>>(X, W, FL, out);
  } else {
    k_exact<<<64, 256, 0, stream>>>(X, W, out);
  }
}